// Round 17
// baseline (348.180 us; speedup 1.0000x reference)
//
#include <hip/hip_runtime.h>

#if __has_builtin(__builtin_amdgcn_exp2f)
#define EXP2F(x) __builtin_amdgcn_exp2f(x)
#else
#define EXP2F(x) exp2f(x)
#endif
#if __has_builtin(__builtin_amdgcn_rcpf)
#define RCPF(x) __builtin_amdgcn_rcpf(x)
#else
#define RCPF(x) (1.0f / (x))
#endif

namespace {

constexpr int B_ = 2048, T_ = 512, D_ = 8, H_ = 20, L_ = 10;
constexpr int NG    = 16;        // batch group per block (MFMA N)
constexpr int PADK  = 24;        // f16 elems per [batch] h row (48B)
constexpr int NW    = 11;        // 10 layer waves + 1 head wave
constexpr int NTHR  = NW * 64;   // 704
constexpr int DEPTH = 8;         // h ring depth
constexpr int SLOT_STRIDE  = L_ * NG * PADK;  // 3840 shorts
constexpr int LAYER_STRIDE = NG * PADK;       // 384 shorts

typedef float    f32x4 __attribute__((ext_vector_type(4)));
typedef _Float16 f16x4 __attribute__((ext_vector_type(4)));  // 2 VGPRs

#define LD4(p) (*reinterpret_cast<const f32x4*>(p))

__device__ __forceinline__ unsigned pack2h(float a, float b) {
    unsigned short ua = __builtin_bit_cast(unsigned short, (_Float16)a);
    unsigned short ub = __builtin_bit_cast(unsigned short, (_Float16)b);
    return (unsigned)ua | ((unsigned)ub << 16);
}
__device__ __forceinline__ float tanh_fast(float x) {
    float e = EXP2F(x * 2.8853900817779268f);
    return fmaf(-2.0f, RCPF(1.0f + e), 1.0f);
}

// K=16 f16 MFMA; B-frag layout == D layout -> h_next packed f16 IS next
// step's B operand (validated R12/R16). NOTE: no underscore before f16.
__device__ __forceinline__ f32x4 mfma16h(f16x4 a, f16x4 b, f32x4 c) {
    return __builtin_amdgcn_mfma_f32_16x16x16f16(a, b, c, 0, 0, 0);
}

__device__ __forceinline__ f16x4 mkfragh(float v0, float v1, float v2, float v3) {
    f16x4 f;
    f[0] = (_Float16)v0; f[1] = (_Float16)v1;
    f[2] = (_Float16)v2; f[3] = (_Float16)v3;
    return f;
}

// bare acquire-poll, returns freshest value (register caching); no s_sleep
__device__ __forceinline__ int wait_ge_ret(int* p, int v) {
    int cur = __hip_atomic_load(p, __ATOMIC_ACQUIRE, __HIP_MEMORY_SCOPE_WORKGROUP);
    while (cur < v)
        cur = __hip_atomic_load(p, __ATOMIC_ACQUIRE, __HIP_MEMORY_SCOPE_WORKGROUP);
    __builtin_amdgcn_sched_barrier(0);
    return cur;
}
// R17: publish with COMPILER-ONLY fence (no s_waitcnt lgkmcnt(0) drain).
// The per-wave DS pipe is FIFO: the h ds_writes issued before this flag
// ds_write commit first; consumer's acquire-poll orders its side. The
// empty asm stops the compiler sinking the h-stores below the flag store.
__device__ __forceinline__ void publish(int* p, int v) {
    asm volatile("" ::: "memory");
    __hip_atomic_store(p, v, __ATOMIC_RELAXED, __HIP_MEMORY_SCOPE_WORKGROUP);
}

// x B-frag, K-cols 0..7 = x in f16 (hi), 8..15 = f32 residual (lo): exact x.
__device__ __forceinline__ f16x4 pack_x4h(f32x4 a, f32x4 b, int g) {
    f16x4 r;
    #pragma unroll
    for (int e = 0; e < 4; ++e) {
        const int k = g * 4 + e;
        const int el = k & 7;
        float f = (el < 4) ? a[el] : b[el - 4];
        _Float16 hi = (_Float16)f;
        r[e] = (k < 8) ? hi : (_Float16)(f - (float)hi);
    }
    return r;
}

// R17 = R16 + two serial-chain cuts (no numeric change):
// (1) 1-deep B0 prefetch: issue ds_read for step t+1 during step t (poll
//     target t+2, cached ~1 real poll / 8 steps) -> ~130cy read latency
//     hides under MFMA+tanh+store instead of heading the chain;
// (2) publish drain removed: compiler fence + relaxed store (DS FIFO
//     ordering) instead of s_waitcnt lgkmcnt(0) per step.
__global__ __launch_bounds__(NTHR) void rnn_async(
    const float* __restrict__ x,      const float* __restrict__ w_ih0,
    const float* __restrict__ w_ih,   const float* __restrict__ w_hh,
    const float* __restrict__ b_ih,   const float* __restrict__ b_hh,
    const float* __restrict__ fc_w,   const float* __restrict__ fc_b,
    const float* __restrict__ l2_w,   const float* __restrict__ l2_b,
    float* __restrict__ out)          // [B,T] flat
{
    __shared__ __align__(16) unsigned short h_lds[DEPTH][L_][NG][PADK]; // 61.4KB
    __shared__ int prog[16];

    const int tid = threadIdx.x;
    const int w   = tid >> 6;       // 0..9 layer wave, 10 head
    const int l   = tid & 63;
    const int col = l & 15;         // batch (B,D) / weight row m (A)
    const int g   = l >> 4;         // k-group (B) / row-group (D)
    const int bg  = blockIdx.x * NG;

    {   // zero ring (h0=0; pad stays 0) + prog
        uint4* p4 = reinterpret_cast<uint4*>(&h_lds[0][0][0][0]);
        for (int i = tid; i < DEPTH * SLOT_STRIDE / 8; i += NTHR)
            p4[i] = make_uint4(0, 0, 0, 0);
        if (tid < 16) prog[tid] = 0;
    }

    // ---- f16 weight fragments: A(m, k=g*4+e) (identical to R16) ----
    f16x4 iA0, iA1, iB0, iB1, hA0, hA1, hB0, hB1;
    f32x4 bias0 = {0.f,0.f,0.f,0.f}, bias1 = bias0, l2v0 = bias0, l2v1 = bias0;
    float l2bv = 0.f;
    const bool m1ok = col < 4;      // Mtile1 rows 16+col valid
    const int k0 = g * 4;
    const f16x4 zh = {(_Float16)0.f, (_Float16)0.f, (_Float16)0.f, (_Float16)0.f};

    if (w < L_) {
        if (w == 0) {               // A[m][k] = w_ih0[m][k&7] (hi & lo cols)
            const int kx = k0 & 7;  // g0:0 g1:4 g2:0 g3:4
            const float* r0 = w_ih0 + col * D_ + kx;
            iA0 = mkfragh(r0[0], r0[1], r0[2], r0[3]);
            const float* r1 = w_ih0 + (16 + col) * D_ + kx;
            iA1 = m1ok ? mkfragh(r1[0], r1[1], r1[2], r1[3]) : zh;
            iB0 = zh; iB1 = zh;
        } else {
            const float* Wm0 = w_ih + ((w - 1) * H_ + col) * H_;
            const float* Wm1 = w_ih + ((w - 1) * H_ + 16 + col) * H_;
            iA0 = mkfragh(Wm0[k0], Wm0[k0+1], Wm0[k0+2], Wm0[k0+3]);
            iA1 = m1ok ? mkfragh(Wm1[k0], Wm1[k0+1], Wm1[k0+2], Wm1[k0+3]) : zh;
            iB0 = (g == 0) ? mkfragh(Wm0[16], Wm0[17], Wm0[18], Wm0[19]) : zh;
            iB1 = (g == 0 && m1ok)
                           ? mkfragh(Wm1[16], Wm1[17], Wm1[18], Wm1[19]) : zh;
        }
        const float* Um0 = w_hh + (w * H_ + col) * H_;
        const float* Um1 = w_hh + (w * H_ + 16 + col) * H_;
        hA0 = mkfragh(Um0[k0], Um0[k0+1], Um0[k0+2], Um0[k0+3]);
        hA1 = m1ok ? mkfragh(Um1[k0], Um1[k0+1], Um1[k0+2], Um1[k0+3]) : zh;
        hB0 = (g == 0) ? mkfragh(Um0[16], Um0[17], Um0[18], Um0[19]) : zh;
        hB1 = (g == 0 && m1ok) ? mkfragh(Um1[16], Um1[17], Um1[18], Um1[19]) : zh;
        #pragma unroll
        for (int r = 0; r < 4; ++r) {
            const int row = g * 4 + r;
            bias0[r] = b_ih[w * H_ + row] + b_hh[w * H_ + row];
            bias1[r] = (g == 0) ? (b_ih[w * H_ + 16 + r] +
                                   b_hh[w * H_ + 16 + r]) : 0.f;
        }
    } else {
        const float* Fm0 = fc_w + col * H_;
        const float* Fm1 = fc_w + (16 + col) * H_;
        iA0 = mkfragh(Fm0[k0], Fm0[k0+1], Fm0[k0+2], Fm0[k0+3]);
        iA1 = m1ok ? mkfragh(Fm1[k0], Fm1[k0+1], Fm1[k0+2], Fm1[k0+3]) : zh;
        iB0 = (g == 0) ? mkfragh(Fm0[16], Fm0[17], Fm0[18], Fm0[19]) : zh;
        iB1 = (g == 0 && m1ok) ? mkfragh(Fm1[16], Fm1[17], Fm1[18], Fm1[19]) : zh;
        hA0 = hA1 = hB0 = hB1 = zh;
        #pragma unroll
        for (int r = 0; r < 4; ++r) {
            bias0[r] = fc_b[g * 4 + r];
            bias1[r] = (g == 0) ? fc_b[16 + r] : 0.f;
            l2v0[r]  = l2_w[g * 4 + r];
            l2v1[r]  = (g == 0) ? l2_w[16 + r] : 0.f;
        }
        l2bv = l2_b[0];
    }

    // wave-0 x prefetch ring: 4 packed slots = times t..t+3
    f16x4 xp0 = zh, xp1 = zh, xp2 = zh, xp3 = zh;
    if (w == 0) {
        const float* xp = x + (size_t)(bg + col) * T_ * D_;
        xp0 = pack_x4h(LD4(xp),          LD4(xp + 4), g);
        xp1 = pack_x4h(LD4(xp + D_),     LD4(xp + D_ + 4), g);
        xp2 = pack_x4h(LD4(xp + 2 * D_), LD4(xp + 2 * D_ + 4), g);
        xp3 = pack_x4h(LD4(xp + 3 * D_), LD4(xp + 3 * D_ + 4), g);
    }

    __syncthreads();  // ONLY barrier

    unsigned short* const hb = &h_lds[0][0][0][0];

    if (w < L_) {
        const int rdB0 = (w ? (w - 1) * LAYER_STRIDE : 0) + col * PADK;
        const int wr0  = w * LAYER_STRIDE + col * PADK + g * 4;
        const int wr1  = w * LAYER_STRIDE + col * PADK + 16;
        uint2 pw = make_uint2(0u, 0u), qw = pw;   // h[t-1] f16 == next B1
        int p_up = 0, p_dn = 0;
        // current-step B0 fragments (prefetched)
        f16x4 cb0 = zh, cb1 = zh;
        if (w == 0) {
            cb0 = xp0;
            xp0 = xp1; xp1 = xp2; xp2 = xp3;   // ring advance for t=0
        } else {
            p_up = wait_ge_ret(&prog[0 + w - 1], 1);
            const unsigned short* rp = hb + 0 * SLOT_STRIDE + rdB0;
            cb0 = __builtin_bit_cast(f16x4,
                    *reinterpret_cast<const uint2*>(rp + g * 4));
            cb1 = (g == 0) ? __builtin_bit_cast(f16x4,
                    *reinterpret_cast<const uint2*>(rp + 16)) : zh;
        }
        for (int t = 0; t < T_; ++t) {
            const int sc = (t & (DEPTH - 1)) * SLOT_STRIDE;
            const f16x4 b1k0 = __builtin_bit_cast(f16x4, pw);  // D->B identity
            const f16x4 b1k1 = __builtin_bit_cast(f16x4, qw);
            // ---- prefetch B0(t+1): issue read now, consume next iter ----
            f16x4 nb0 = zh, nb1 = zh;
            if (w == 0) {
                nb0 = xp0;
                xp0 = xp1; xp1 = xp2;
                if (t + 4 < T_) {   // refill x time t+4 (4-slot ring)
                    const float* xq = x + ((size_t)(bg + col) * T_ + t + 4) * D_;
                    xp2 = pack_x4h(LD4(xq), LD4(xq + 4), g);
                }
            } else if (t + 1 < T_) {
                if (p_up < t + 2) p_up = wait_ge_ret(&prog[w - 1], t + 2);
                const unsigned short* rp =
                    hb + ((t + 1) & (DEPTH - 1)) * SLOT_STRIDE + rdB0;
                nb0 = __builtin_bit_cast(f16x4,
                        *reinterpret_cast<const uint2*>(rp + g * 4));
                nb1 = (g == 0) ? __builtin_bit_cast(f16x4,
                        *reinterpret_cast<const uint2*>(rp + 16)) : zh;
            }
            // ---- 8 MFMA (6 for w==0): two 3-4 deep chains ----
            f32x4 acc0 = mfma16h(iA0, cb0, bias0);
            f32x4 acc1 = mfma16h(iA1, cb0, bias1);
            if (w != 0) {           // wave-uniform
                acc0 = mfma16h(iB0, cb1, acc0);
                acc1 = mfma16h(iB1, cb1, acc1);
            }
            acc0 = mfma16h(hA0, b1k0, acc0);
            acc1 = mfma16h(hA1, b1k0, acc1);
            acc0 = mfma16h(hB0, b1k1, acc0);
            acc1 = mfma16h(hB1, b1k1, acc1);
            pw.x = pack2h(tanh_fast(acc0[0]), tanh_fast(acc0[1]));
            pw.y = pack2h(tanh_fast(acc0[2]), tanh_fast(acc0[3]));
            qw.x = pack2h(tanh_fast(acc1[0]), tanh_fast(acc1[1]));
            qw.y = pack2h(tanh_fast(acc1[2]), tanh_fast(acc1[3]));
            // WAR: slot sc reused from t-DEPTH
            if (t >= DEPTH && p_dn < t - DEPTH + 1)
                p_dn = wait_ge_ret(&prog[w + 1], t - DEPTH + 1);
            *reinterpret_cast<uint2*>(hb + sc + wr0) = pw;
            if (g == 0) *reinterpret_cast<uint2*>(hb + sc + wr1) = qw;
            if (l == 0) publish(&prog[w], t + 1);
            cb0 = nb0; cb1 = nb1;
        }
    } else {
        // head wave: y[t] from h[9][t], 1-deep prefetched
        const int rdH = (L_ - 1) * LAYER_STRIDE + col * PADK;
        int p_up = wait_ge_ret(&prog[L_ - 1], 1);
        f16x4 cb0, cb1;
        {
            const unsigned short* rp = hb + 0 * SLOT_STRIDE + rdH;
            cb0 = __builtin_bit_cast(f16x4,
                    *reinterpret_cast<const uint2*>(rp + g * 4));
            cb1 = (g == 0) ? __builtin_bit_cast(f16x4,
                    *reinterpret_cast<const uint2*>(rp + 16)) : zh;
        }
        for (int t = 0; t < T_; ++t) {
            f16x4 nb0 = zh, nb1 = zh;
            if (t + 1 < T_) {
                if (p_up < t + 2) p_up = wait_ge_ret(&prog[L_ - 1], t + 2);
                const unsigned short* rp =
                    hb + ((t + 1) & (DEPTH - 1)) * SLOT_STRIDE + rdH;
                nb0 = __builtin_bit_cast(f16x4,
                        *reinterpret_cast<const uint2*>(rp + g * 4));
                nb1 = (g == 0) ? __builtin_bit_cast(f16x4,
                        *reinterpret_cast<const uint2*>(rp + 16)) : zh;
            }
            f32x4 z0 = mfma16h(iA0, cb0, bias0);
            f32x4 z1 = mfma16h(iA1, cb0, bias1);
            z0 = mfma16h(iB0, cb1, z0);
            z1 = mfma16h(iB1, cb1, z1);
            float part = 0.f;
            #pragma unroll
            for (int r = 0; r < 4; ++r) {
                part = fmaf(l2v0[r], fmaxf(z0[r], 0.f), part);
                part = fmaf(l2v1[r], fmaxf(z1[r], 0.f), part);
            }
            part += __shfl_xor(part, 16);
            part += __shfl_xor(part, 32);
            if (l < NG) out[(size_t)(bg + l) * T_ + t] = part + l2bv;
            // publish = "h[9][t] consumed" (read completed before MFMA use)
            if (l == 0) publish(&prog[L_], t + 1);
            cb0 = nb0; cb1 = nb1;
        }
    }
}

}  // namespace

extern "C" void kernel_launch(void* const* d_in, const int* in_sizes, int n_in,
                              void* d_out, int out_size, void* d_ws, size_t ws_size,
                              hipStream_t stream) {
    const float* x     = (const float*)d_in[0];
    const float* w_ih0 = (const float*)d_in[1];
    const float* w_ih  = (const float*)d_in[2];
    const float* w_hh  = (const float*)d_in[3];
    const float* b_ih  = (const float*)d_in[4];
    const float* b_hh  = (const float*)d_in[5];
    const float* fc_w  = (const float*)d_in[6];
    const float* fc_b  = (const float*)d_in[7];
    const float* l2_w  = (const float*)d_in[8];
    const float* l2_b  = (const float*)d_in[9];
    float* out = (float*)d_out;

    const int grid = B_ / NG;  // 128
    hipLaunchKernelGGL(rnn_async, dim3(grid), dim3(NTHR), 0, stream,
                       x, w_ih0, w_ih, w_hh, b_ih, b_hh, fc_w, fc_b,
                       l2_w, l2_b, out);
}